// Round 1
// baseline (491.926 us; speedup 1.0000x reference)
//
#include <hip/hip_runtime.h>

#define N_NODES 65536
#define N_EDGES 1048576
constexpr float NEG = 0.2f;
constexpr float EPS_ = 1e-16f;

// ---------------- CSR build ----------------

__global__ __launch_bounds__(256) void hist_kernel(const int* __restrict__ ei,
                                                   int* __restrict__ counts) {
    int e = blockIdx.x * 256 + threadIdx.x;
    atomicAdd(&counts[ei[N_EDGES + e]], 1);
}

__global__ __launch_bounds__(1024) void scan_a(const int* __restrict__ counts,
                                               int* __restrict__ row_ptr,
                                               int* __restrict__ bsum) {
    __shared__ int sm[1024];
    int t = threadIdx.x, i = blockIdx.x * 1024 + t;
    int v = counts[i];
    sm[t] = v;
    __syncthreads();
    for (int off = 1; off < 1024; off <<= 1) {
        int u = (t >= off) ? sm[t - off] : 0;
        __syncthreads();
        sm[t] += u;
        __syncthreads();
    }
    row_ptr[i] = sm[t] - v;                 // block-local exclusive prefix
    if (t == 1023) bsum[blockIdx.x] = sm[t];
}

__global__ __launch_bounds__(64) void scan_b(int* __restrict__ bsum,
                                             int* __restrict__ row_ptr) {
    int t = threadIdx.x;
    int v = bsum[t];
    int incl = v;
    #pragma unroll
    for (int off = 1; off < 64; off <<= 1) {
        int u = __shfl_up(incl, off);
        if (t >= off) incl += u;
    }
    bsum[t] = incl - v;                     // exclusive block offsets
    if (t == 63) row_ptr[N_NODES] = incl;   // total == E
}

__global__ __launch_bounds__(1024) void scan_c(int* __restrict__ row_ptr,
                                               const int* __restrict__ bsum,
                                               int* __restrict__ offsets) {
    int i = blockIdx.x * 1024 + threadIdx.x;
    int v = row_ptr[i] + bsum[blockIdx.x];
    row_ptr[i] = v;
    offsets[i] = v;
}

__global__ __launch_bounds__(256) void scatter_kernel(const int* __restrict__ ei,
                                                      int* __restrict__ offsets,
                                                      int* __restrict__ csr_src) {
    int e = blockIdx.x * 256 + threadIdx.x;
    int s = ei[e], d = ei[N_EDGES + e];
    int pos = atomicAdd(&offsets[d], 1);
    csr_src[pos] = s;
}

// ---------------- GEMM (K=128 fixed, fp32 vector ALU) ----------------
// thread = 4 nodes x 4 channels; W staged in LDS; x read as float4 (L1-broadcast).

template <int OUTC>
__global__ __launch_bounds__(256) void gemm_kernel(const float* __restrict__ X,
                                                   const float* __restrict__ W,
                                                   float* __restrict__ H) {
    extern __shared__ float Ws[];
    constexpr int CQ = OUTC / 4;                    // channel-quads per node
    constexpr int NODES_PER_BLOCK = (256 / CQ) * 4;
    for (int i = threadIdx.x; i < 128 * OUTC / 4; i += 256)
        ((float4*)Ws)[i] = ((const float4*)W)[i];
    __syncthreads();
    int cq = threadIdx.x % CQ;
    int nq = threadIdx.x / CQ;
    int node0 = blockIdx.x * NODES_PER_BLOCK + nq * 4;
    float acc[4][4] = {};
    const float4* x4 = (const float4*)X;
    for (int k4 = 0; k4 < 32; ++k4) {
        float4 xv[4];
        #pragma unroll
        for (int i = 0; i < 4; ++i) xv[i] = x4[(node0 + i) * 32 + k4];
        #pragma unroll
        for (int j = 0; j < 4; ++j) {
            float4 wv = ((const float4*)(Ws + (k4 * 4 + j) * OUTC))[cq];
            #pragma unroll
            for (int i = 0; i < 4; ++i) {
                float xs = ((const float*)&xv[i])[j];
                acc[i][0] += xs * wv.x;
                acc[i][1] += xs * wv.y;
                acc[i][2] += xs * wv.z;
                acc[i][3] += xs * wv.w;
            }
        }
    }
    #pragma unroll
    for (int i = 0; i < 4; ++i) {
        float4 o = make_float4(acc[i][0], acc[i][1], acc[i][2], acc[i][3]);
        ((float4*)(H + (node0 + i) * OUTC))[cq] = o;
    }
}

// ---------------- attention logits ----------------
// layer 1: wave per node, lane holds channels 2l,2l+1 (head = l>>4); 16-lane xor-reduce.

__global__ __launch_bounds__(256) void att1_kernel(const float* __restrict__ h1,
                                                   const float* __restrict__ as_w,
                                                   const float* __restrict__ ad_w,
                                                   float* __restrict__ a_src,
                                                   float* __restrict__ a_dst) {
    int wave = (blockIdx.x * 256 + threadIdx.x) >> 6;
    int lane = threadIdx.x & 63;
    float2 hv = *(const float2*)(h1 + wave * 128 + lane * 2);
    float2 sw = *(const float2*)(as_w + lane * 2);
    float2 dw = *(const float2*)(ad_w + lane * 2);
    float ps = hv.x * sw.x + hv.y * sw.y;
    float pd = hv.x * dw.x + hv.y * dw.y;
    #pragma unroll
    for (int m = 1; m < 16; m <<= 1) {
        ps += __shfl_xor(ps, m);
        pd += __shfl_xor(pd, m);
    }
    if ((lane & 15) == 0) {
        a_src[wave * 4 + (lane >> 4)] = ps;
        a_dst[wave * 4 + (lane >> 4)] = pd;
    }
}

__global__ __launch_bounds__(256) void att2_kernel(const float* __restrict__ h2,
                                                   const float* __restrict__ as_w,
                                                   const float* __restrict__ ad_w,
                                                   float* __restrict__ a_src,
                                                   float* __restrict__ a_dst) {
    int wave = (blockIdx.x * 256 + threadIdx.x) >> 6;
    int lane = threadIdx.x & 63;
    float v = h2[wave * 64 + lane];
    float ps = v * as_w[lane];
    float pd = v * ad_w[lane];
    #pragma unroll
    for (int m = 1; m < 64; m <<= 1) {
        ps += __shfl_xor(ps, m);
        pd += __shfl_xor(pd, m);
    }
    if (lane == 0) {
        a_src[wave] = ps;
        a_dst[wave] = pd;
    }
}

// ---------------- edge aggregation (softmax fused, no atomics) ----------------
// wave per dst node; unnormalized accumulate; per-lane denom (identical within head group).

__global__ __launch_bounds__(256) void agg1_kernel(const int* __restrict__ row_ptr,
                                                   const int* __restrict__ csr_src,
                                                   const float* __restrict__ h1,
                                                   const float* __restrict__ a_src,
                                                   const float* __restrict__ a_dst,
                                                   const float* __restrict__ b1,
                                                   float* __restrict__ x2) {
    int n = (blockIdx.x * 256 + threadIdx.x) >> 6;
    int lane = threadIdx.x & 63;
    int hd = lane >> 4;        // head of this lane's channels
    int c0 = lane * 2;         // channels c0, c0+1
    float ad = a_dst[n * 4 + hd];
    int e = row_ptr[n], end = row_ptr[n + 1];
    float acc0 = 0.f, acc1 = 0.f, denom = 0.f;
    while (e < end) {
        int m = end - e;
        if (m > 64) m = 64;
        int s_l = (lane < m) ? csr_src[e + lane] : 0;
        for (int j = 0; j < m; ++j) {
            int s = __shfl(s_l, j);
            float logit = a_src[s * 4 + hd] + ad;
            float w = __expf(logit > 0.f ? logit : NEG * logit);
            float2 hv = *(const float2*)(h1 + s * 128 + c0);
            denom += w;
            acc0 += w * hv.x;
            acc1 += w * hv.y;
        }
        e += 64;
    }
    float inv = 1.f / (denom + EPS_);
    float o0 = acc0 * inv + b1[c0];
    float o1 = acc1 * inv + b1[c0 + 1];
    o0 = 1.f / (1.f + __expf(-o0));
    o1 = 1.f / (1.f + __expf(-o1));
    *(float2*)(x2 + n * 128 + c0) = make_float2(o0, o1);
}

__global__ __launch_bounds__(256) void agg2_kernel(const int* __restrict__ row_ptr,
                                                   const int* __restrict__ csr_src,
                                                   const float* __restrict__ h2,
                                                   const float* __restrict__ a_src,
                                                   const float* __restrict__ a_dst,
                                                   const float* __restrict__ b2,
                                                   float* __restrict__ out) {
    int n = (blockIdx.x * 256 + threadIdx.x) >> 6;
    int lane = threadIdx.x & 63;
    float ad = a_dst[n];
    int e = row_ptr[n], end = row_ptr[n + 1];
    float acc = 0.f, denom = 0.f;
    while (e < end) {
        int m = end - e;
        if (m > 64) m = 64;
        int s_l = (lane < m) ? csr_src[e + lane] : 0;
        for (int j = 0; j < m; ++j) {
            int s = __shfl(s_l, j);
            float logit = a_src[s] + ad;
            float w = __expf(logit > 0.f ? logit : NEG * logit);
            denom += w;
            acc += w * h2[s * 64 + lane];
        }
        e += 64;
    }
    float o = acc / (denom + EPS_) + b2[lane];
    out[n * 64 + lane] = 1.f / (1.f + __expf(-o));
}

// ---------------- launch ----------------

extern "C" void kernel_launch(void* const* d_in, const int* in_sizes, int n_in,
                              void* d_out, int out_size, void* d_ws, size_t ws_size,
                              hipStream_t stream) {
    (void)in_sizes; (void)n_in; (void)out_size; (void)ws_size;
    const float* x   = (const float*)d_in[0];
    const int*   ei  = (const int*)d_in[1];
    const float* W1  = (const float*)d_in[2];
    const float* as1 = (const float*)d_in[3];
    const float* ad1 = (const float*)d_in[4];
    const float* b1  = (const float*)d_in[5];
    const float* W2  = (const float*)d_in[6];
    const float* as2 = (const float*)d_in[7];
    const float* ad2 = (const float*)d_in[8];
    const float* b2  = (const float*)d_in[9];
    float* out = (float*)d_out;

    char* p = (char*)d_ws;
    auto alloc = [&](size_t bytes) -> void* {
        void* r = (void*)p;
        p += (bytes + 255) & ~(size_t)255;
        return r;
    };
    int* counts    = (int*)alloc((size_t)N_NODES * 4);
    int* row_ptr   = (int*)alloc((size_t)(N_NODES + 1) * 4);
    int* offsets   = (int*)alloc((size_t)N_NODES * 4);
    int* bsum      = (int*)alloc(64 * 4);
    int* csr_src   = (int*)alloc((size_t)N_EDGES * 4);
    float* h1      = (float*)alloc((size_t)N_NODES * 128 * 4);
    float* a_src1  = (float*)alloc((size_t)N_NODES * 4 * 4);
    float* a_dst1  = (float*)alloc((size_t)N_NODES * 4 * 4);
    float* x2      = (float*)alloc((size_t)N_NODES * 128 * 4);
    float* h2      = (float*)alloc((size_t)N_NODES * 64 * 4);
    float* a_src2  = (float*)alloc((size_t)N_NODES * 4);
    float* a_dst2  = (float*)alloc((size_t)N_NODES * 4);

    // CSR build (shared by both layers)
    hipMemsetAsync(counts, 0, (size_t)N_NODES * 4, stream);
    hist_kernel<<<N_EDGES / 256, 256, 0, stream>>>(ei, counts);
    scan_a<<<64, 1024, 0, stream>>>(counts, row_ptr, bsum);
    scan_b<<<1, 64, 0, stream>>>(bsum, row_ptr);
    scan_c<<<64, 1024, 0, stream>>>(row_ptr, bsum, offsets);
    scatter_kernel<<<N_EDGES / 256, 256, 0, stream>>>(ei, offsets, csr_src);

    // layer 1
    gemm_kernel<128><<<N_NODES / 32, 256, 64 * 1024, stream>>>(x, W1, h1);
    att1_kernel<<<N_NODES / 4, 256, 0, stream>>>(h1, as1, ad1, a_src1, a_dst1);
    agg1_kernel<<<N_NODES / 4, 256, 0, stream>>>(row_ptr, csr_src, h1, a_src1, a_dst1, b1, x2);

    // layer 2
    gemm_kernel<64><<<N_NODES / 64, 256, 32 * 1024, stream>>>(x2, W2, h2);
    att2_kernel<<<N_NODES / 4, 256, 0, stream>>>(h2, as2, ad2, a_src2, a_dst2);
    agg2_kernel<<<N_NODES / 4, 256, 0, stream>>>(row_ptr, csr_src, h2, a_src2, a_dst2, b2, out);
}

// Round 4
// 411.244 us; speedup vs baseline: 1.1962x; 1.1962x over previous
//
#include <hip/hip_runtime.h>

#define N_NODES 65536
#define N_EDGES 1048576
constexpr float NEG = 0.2f;
constexpr float EPS_ = 1e-16f;

// bf16 helpers (bit tricks; no NaN inputs here)
__device__ __forceinline__ unsigned short f2bf(float f) {
    unsigned int u = __float_as_uint(f);
    return (unsigned short)((u + 0x7fffu + ((u >> 16) & 1u)) >> 16);
}
__device__ __forceinline__ float bflo(unsigned int p) { return __uint_as_float(p << 16); }
__device__ __forceinline__ float bfhi(unsigned int p) { return __uint_as_float(p & 0xffff0000u); }
__device__ __forceinline__ float bf2f(unsigned short u) { return __uint_as_float((unsigned int)u << 16); }
__device__ __forceinline__ float lrelu_exp(float l) { return __expf(fmaxf(l, NEG * l)); }

// ---------------- CSR build ----------------

__global__ __launch_bounds__(256) void hist_kernel(const int* __restrict__ ei,
                                                   int* __restrict__ counts) {
    int e = blockIdx.x * 256 + threadIdx.x;
    atomicAdd(&counts[ei[N_EDGES + e]], 1);
}

__global__ __launch_bounds__(1024) void scan_a(const int* __restrict__ counts,
                                               int* __restrict__ row_ptr,
                                               int* __restrict__ bsum) {
    __shared__ int sm[1024];
    int t = threadIdx.x, i = blockIdx.x * 1024 + t;
    int v = counts[i];
    sm[t] = v;
    __syncthreads();
    for (int off = 1; off < 1024; off <<= 1) {
        int u = (t >= off) ? sm[t - off] : 0;
        __syncthreads();
        sm[t] += u;
        __syncthreads();
    }
    row_ptr[i] = sm[t] - v;
    if (t == 1023) bsum[blockIdx.x] = sm[t];
}

__global__ __launch_bounds__(64) void scan_b(int* __restrict__ bsum,
                                             int* __restrict__ row_ptr) {
    int t = threadIdx.x;
    int v = bsum[t];
    int incl = v;
    #pragma unroll
    for (int off = 1; off < 64; off <<= 1) {
        int u = __shfl_up(incl, off);
        if (t >= off) incl += u;
    }
    bsum[t] = incl - v;
    if (t == 63) row_ptr[N_NODES] = incl;
}

__global__ __launch_bounds__(1024) void scan_c(int* __restrict__ row_ptr,
                                               const int* __restrict__ bsum,
                                               int* __restrict__ offsets) {
    int i = blockIdx.x * 1024 + threadIdx.x;
    int v = row_ptr[i] + bsum[blockIdx.x];
    row_ptr[i] = v;
    offsets[i] = v;
}

__global__ __launch_bounds__(256) void scatter_kernel(const int* __restrict__ ei,
                                                      int* __restrict__ offsets,
                                                      int* __restrict__ csr_src) {
    int e = blockIdx.x * 256 + threadIdx.x;
    int s = ei[e], d = ei[N_EDGES + e];
    int pos = atomicAdd(&offsets[d], 1);
    csr_src[pos] = s;
}

// ---------------- GEMM (K=128 fixed, fp32 vector ALU, bf16 output) ----------------

template <int OUTC>
__global__ __launch_bounds__(256) void gemm_kernel(const float* __restrict__ X,
                                                   const float* __restrict__ W,
                                                   unsigned short* __restrict__ H) {
    extern __shared__ float Ws[];
    constexpr int CQ = OUTC / 4;
    constexpr int NODES_PER_BLOCK = (256 / CQ) * 4;
    for (int i = threadIdx.x; i < 128 * OUTC / 4; i += 256)
        ((float4*)Ws)[i] = ((const float4*)W)[i];
    __syncthreads();
    int cq = threadIdx.x % CQ;
    int nq = threadIdx.x / CQ;
    int node0 = blockIdx.x * NODES_PER_BLOCK + nq * 4;
    float acc[4][4] = {};
    const float4* x4 = (const float4*)X;
    for (int k4 = 0; k4 < 32; ++k4) {
        float4 xv[4];
        #pragma unroll
        for (int i = 0; i < 4; ++i) xv[i] = x4[(node0 + i) * 32 + k4];
        #pragma unroll
        for (int j = 0; j < 4; ++j) {
            float4 wv = ((const float4*)(Ws + (k4 * 4 + j) * OUTC))[cq];
            #pragma unroll
            for (int i = 0; i < 4; ++i) {
                float xs = ((const float*)&xv[i])[j];
                acc[i][0] += xs * wv.x;
                acc[i][1] += xs * wv.y;
                acc[i][2] += xs * wv.z;
                acc[i][3] += xs * wv.w;
            }
        }
    }
    #pragma unroll
    for (int i = 0; i < 4; ++i) {
        ushort4 o;
        o.x = f2bf(acc[i][0]);
        o.y = f2bf(acc[i][1]);
        o.z = f2bf(acc[i][2]);
        o.w = f2bf(acc[i][3]);
        ((ushort4*)(H + (size_t)(node0 + i) * OUTC))[cq] = o;
    }
}

// ---------------- attention logits (bf16 h) ----------------

__global__ __launch_bounds__(256) void att1_kernel(const unsigned int* __restrict__ h1u,
                                                   const float* __restrict__ as_w,
                                                   const float* __restrict__ ad_w,
                                                   float* __restrict__ a_src,
                                                   float* __restrict__ a_dst) {
    int wave = (blockIdx.x * 256 + threadIdx.x) >> 6;
    int lane = threadIdx.x & 63;
    unsigned int p = h1u[wave * 64 + lane];
    float h0 = bflo(p), h1v = bfhi(p);
    float2 sw = *(const float2*)(as_w + lane * 2);
    float2 dw = *(const float2*)(ad_w + lane * 2);
    float ps = h0 * sw.x + h1v * sw.y;
    float pd = h0 * dw.x + h1v * dw.y;
    #pragma unroll
    for (int m = 1; m < 16; m <<= 1) {
        ps += __shfl_xor(ps, m);
        pd += __shfl_xor(pd, m);
    }
    if ((lane & 15) == 0) {
        a_src[wave * 4 + (lane >> 4)] = ps;
        a_dst[wave * 4 + (lane >> 4)] = pd;
    }
}

__global__ __launch_bounds__(256) void att2_kernel(const unsigned short* __restrict__ h2u,
                                                   const float* __restrict__ as_w,
                                                   const float* __restrict__ ad_w,
                                                   float* __restrict__ a_src,
                                                   float* __restrict__ a_dst) {
    int wave = (blockIdx.x * 256 + threadIdx.x) >> 6;
    int lane = threadIdx.x & 63;
    float v = bf2f(h2u[wave * 64 + lane]);
    float ps = v * as_w[lane];
    float pd = v * ad_w[lane];
    #pragma unroll
    for (int m = 1; m < 64; m <<= 1) {
        ps += __shfl_xor(ps, m);
        pd += __shfl_xor(pd, m);
    }
    if (lane == 0) {
        a_src[wave] = ps;
        a_dst[wave] = pd;
    }
}

// ---------------- edge aggregation (softmax fused, bf16 gather, 4x MLP) ----------------

__global__ __launch_bounds__(256) void agg1_kernel(const int* __restrict__ row_ptr,
                                                   const int* __restrict__ csr_src,
                                                   const unsigned int* __restrict__ h1u,
                                                   const float* __restrict__ a_src,
                                                   const float* __restrict__ a_dst,
                                                   const float* __restrict__ b1,
                                                   float* __restrict__ x2) {
    int n = (blockIdx.x * 256 + threadIdx.x) >> 6;
    int lane = threadIdx.x & 63;
    int hd = lane >> 4;
    int c0 = lane * 2;
    float ad = a_dst[n * 4 + hd];
    int e = row_ptr[n], end = row_ptr[n + 1];
    float acc0 = 0.f, acc1 = 0.f, denom = 0.f;
    while (e < end) {
        int m = end - e;
        if (m > 64) m = 64;
        int s_l = (lane < m) ? csr_src[e + lane] : 0;
        int j = 0;
        for (; j + 4 <= m; j += 4) {
            int s0 = __shfl(s_l, j + 0);
            int s1 = __shfl(s_l, j + 1);
            int s2 = __shfl(s_l, j + 2);
            int s3 = __shfl(s_l, j + 3);
            float l0 = a_src[s0 * 4 + hd] + ad;
            float l1 = a_src[s1 * 4 + hd] + ad;
            float l2 = a_src[s2 * 4 + hd] + ad;
            float l3 = a_src[s3 * 4 + hd] + ad;
            unsigned int p0 = h1u[(size_t)s0 * 64 + lane];
            unsigned int p1 = h1u[(size_t)s1 * 64 + lane];
            unsigned int p2 = h1u[(size_t)s2 * 64 + lane];
            unsigned int p3 = h1u[(size_t)s3 * 64 + lane];
            float w0 = lrelu_exp(l0), w1 = lrelu_exp(l1);
            float w2 = lrelu_exp(l2), w3 = lrelu_exp(l3);
            denom += w0 + w1 + w2 + w3;
            acc0 += w0 * bflo(p0) + w1 * bflo(p1) + w2 * bflo(p2) + w3 * bflo(p3);
            acc1 += w0 * bfhi(p0) + w1 * bfhi(p1) + w2 * bfhi(p2) + w3 * bfhi(p3);
        }
        for (; j < m; ++j) {
            int s = __shfl(s_l, j);
            float w = lrelu_exp(a_src[s * 4 + hd] + ad);
            unsigned int p = h1u[(size_t)s * 64 + lane];
            denom += w;
            acc0 += w * bflo(p);
            acc1 += w * bfhi(p);
        }
        e += 64;
    }
    float inv = 1.f / (denom + EPS_);
    float o0 = acc0 * inv + b1[c0];
    float o1 = acc1 * inv + b1[c0 + 1];
    o0 = 1.f / (1.f + __expf(-o0));
    o1 = 1.f / (1.f + __expf(-o1));
    *(float2*)(x2 + (size_t)n * 128 + c0) = make_float2(o0, o1);
}

__global__ __launch_bounds__(256) void agg2_kernel(const int* __restrict__ row_ptr,
                                                   const int* __restrict__ csr_src,
                                                   const unsigned short* __restrict__ h2u,
                                                   const float* __restrict__ a_src,
                                                   const float* __restrict__ a_dst,
                                                   const float* __restrict__ b2,
                                                   float* __restrict__ out) {
    int n = (blockIdx.x * 256 + threadIdx.x) >> 6;
    int lane = threadIdx.x & 63;
    float ad = a_dst[n];
    int e = row_ptr[n], end = row_ptr[n + 1];
    float acc = 0.f, denom = 0.f;
    while (e < end) {
        int m = end - e;
        if (m > 64) m = 64;
        int s_l = (lane < m) ? csr_src[e + lane] : 0;
        int j = 0;
        for (; j + 4 <= m; j += 4) {
            int s0 = __shfl(s_l, j + 0);
            int s1 = __shfl(s_l, j + 1);
            int s2 = __shfl(s_l, j + 2);
            int s3 = __shfl(s_l, j + 3);
            float l0 = a_src[s0] + ad;
            float l1 = a_src[s1] + ad;
            float l2 = a_src[s2] + ad;
            float l3 = a_src[s3] + ad;
            float v0 = bf2f(h2u[(size_t)s0 * 64 + lane]);
            float v1 = bf2f(h2u[(size_t)s1 * 64 + lane]);
            float v2 = bf2f(h2u[(size_t)s2 * 64 + lane]);
            float v3 = bf2f(h2u[(size_t)s3 * 64 + lane]);
            float w0 = lrelu_exp(l0), w1 = lrelu_exp(l1);
            float w2 = lrelu_exp(l2), w3 = lrelu_exp(l3);
            denom += w0 + w1 + w2 + w3;
            acc += w0 * v0 + w1 * v1 + w2 * v2 + w3 * v3;
        }
        for (; j < m; ++j) {
            int s = __shfl(s_l, j);
            float w = lrelu_exp(a_src[s] + ad);
            float v = bf2f(h2u[(size_t)s * 64 + lane]);
            denom += w;
            acc += w * v;
        }
        e += 64;
    }
    float o = acc / (denom + EPS_) + b2[lane];
    out[(size_t)n * 64 + lane] = 1.f / (1.f + __expf(-o));
}

// ---------------- launch ----------------

extern "C" void kernel_launch(void* const* d_in, const int* in_sizes, int n_in,
                              void* d_out, int out_size, void* d_ws, size_t ws_size,
                              hipStream_t stream) {
    (void)in_sizes; (void)n_in; (void)out_size; (void)ws_size;
    const float* x   = (const float*)d_in[0];
    const int*   ei  = (const int*)d_in[1];
    const float* W1  = (const float*)d_in[2];
    const float* as1 = (const float*)d_in[3];
    const float* ad1 = (const float*)d_in[4];
    const float* b1  = (const float*)d_in[5];
    const float* W2  = (const float*)d_in[6];
    const float* as2 = (const float*)d_in[7];
    const float* ad2 = (const float*)d_in[8];
    const float* b2  = (const float*)d_in[9];
    float* out = (float*)d_out;

    char* p = (char*)d_ws;
    auto alloc = [&](size_t bytes) -> void* {
        void* r = (void*)p;
        p += (bytes + 255) & ~(size_t)255;
        return r;
    };
    int* counts    = (int*)alloc((size_t)N_NODES * 4);
    int* row_ptr   = (int*)alloc((size_t)(N_NODES + 1) * 4);
    int* offsets   = (int*)alloc((size_t)N_NODES * 4);
    int* bsum      = (int*)alloc(64 * 4);
    int* csr_src   = (int*)alloc((size_t)N_EDGES * 4);
    unsigned short* h1 = (unsigned short*)alloc((size_t)N_NODES * 128 * 2);  // bf16
    float* a_src1  = (float*)alloc((size_t)N_NODES * 4 * 4);
    float* a_dst1  = (float*)alloc((size_t)N_NODES * 4 * 4);
    float* x2      = (float*)alloc((size_t)N_NODES * 128 * 4);
    unsigned short* h2 = (unsigned short*)alloc((size_t)N_NODES * 64 * 2);   // bf16
    float* a_src2  = (float*)alloc((size_t)N_NODES * 4);
    float* a_dst2  = (float*)alloc((size_t)N_NODES * 4);

    // CSR build (shared by both layers)
    hipMemsetAsync(counts, 0, (size_t)N_NODES * 4, stream);
    hist_kernel<<<N_EDGES / 256, 256, 0, stream>>>(ei, counts);
    scan_a<<<64, 1024, 0, stream>>>(counts, row_ptr, bsum);
    scan_b<<<1, 64, 0, stream>>>(bsum, row_ptr);
    scan_c<<<64, 1024, 0, stream>>>(row_ptr, bsum, offsets);
    scatter_kernel<<<N_EDGES / 256, 256, 0, stream>>>(ei, offsets, csr_src);

    // layer 1
    gemm_kernel<128><<<N_NODES / 32, 256, 64 * 1024, stream>>>(x, W1, h1);
    att1_kernel<<<N_NODES / 4, 256, 0, stream>>>((const unsigned int*)h1, as1, ad1, a_src1, a_dst1);
    agg1_kernel<<<N_NODES / 4, 256, 0, stream>>>(row_ptr, csr_src, (const unsigned int*)h1,
                                                 a_src1, a_dst1, b1, x2);

    // layer 2
    gemm_kernel<64><<<N_NODES / 64, 256, 32 * 1024, stream>>>(x2, W2, h2);
    att2_kernel<<<N_NODES / 4, 256, 0, stream>>>(h2, as2, ad2, a_src2, a_dst2);
    agg2_kernel<<<N_NODES / 4, 256, 0, stream>>>(row_ptr, csr_src, h2, a_src2, a_dst2, b2, out);
}

// Round 6
// 292.311 us; speedup vs baseline: 1.6829x; 1.4069x over previous
//
#include <hip/hip_runtime.h>

#define N_NODES 65536
#define N_EDGES 1048576
#define NBUCK 256                 // coarse buckets (dst>>8), 256 nodes each
#define PBLOCKS 256               // partition blocks
#define EPB (N_EDGES / PBLOCKS)   // 4096 edges per partition block
#define K4CAP 6144                // finalize LDS staging capacity (mean 4096, sigma 64)
constexpr float NEG = 0.2f;
constexpr float EPS_ = 1e-16f;

// bf16 helpers (bit tricks; no NaN inputs here)
__device__ __forceinline__ unsigned short f2bf(float f) {
    unsigned int u = __float_as_uint(f);
    return (unsigned short)((u + 0x7fffu + ((u >> 16) & 1u)) >> 16);
}
__device__ __forceinline__ float bflo(unsigned int p) { return __uint_as_float(p << 16); }
__device__ __forceinline__ float bfhi(unsigned int p) { return __uint_as_float(p & 0xffff0000u); }
__device__ __forceinline__ float bf2f(unsigned short u) { return __uint_as_float((unsigned int)u << 16); }
__device__ __forceinline__ float lrelu_exp(float l) { return __expf(fmaxf(l, NEG * l)); }

// ---------------- CSR build: radix partition by dst>>8, no global atomics ----------------

// (bucket, block) histogram matrix, bucket-major: hist_mat[b*PBLOCKS + blk]
__global__ __launch_bounds__(256) void coarse_hist(const int* __restrict__ ei,
                                                   int* __restrict__ hist_mat) {
    __shared__ int h[NBUCK];
    int t = threadIdx.x;
    h[t] = 0;
    __syncthreads();
    int base = blockIdx.x * EPB;
    #pragma unroll
    for (int i = 0; i < EPB / 256; ++i) {
        int d = ei[N_EDGES + base + i * 256 + t];
        atomicAdd(&h[d >> 8], 1);
    }
    __syncthreads();
    hist_mat[t * PBLOCKS + blockIdx.x] = h[t];
}

// exclusive scan of 65536 ints: block-local (scan_a) + block offsets (scan_b) + fixup (scan_c)
__global__ __launch_bounds__(1024) void scan_a(const int* __restrict__ in,
                                               int* __restrict__ out,
                                               int* __restrict__ bsum) {
    __shared__ int sm[1024];
    int t = threadIdx.x, i = blockIdx.x * 1024 + t;
    int v = in[i];
    sm[t] = v;
    __syncthreads();
    for (int off = 1; off < 1024; off <<= 1) {
        int u = (t >= off) ? sm[t - off] : 0;
        __syncthreads();
        sm[t] += u;
        __syncthreads();
    }
    out[i] = sm[t] - v;
    if (t == 1023) bsum[blockIdx.x] = sm[t];
}

__global__ __launch_bounds__(64) void scan_b(int* __restrict__ bsum,
                                             int* __restrict__ row_ptr) {
    int t = threadIdx.x;
    int v = bsum[t];
    int incl = v;
    #pragma unroll
    for (int off = 1; off < 64; off <<= 1) {
        int u = __shfl_up(incl, off);
        if (t >= off) incl += u;
    }
    bsum[t] = incl - v;
    if (t == 63) row_ptr[N_NODES] = incl;   // == N_EDGES
}

__global__ __launch_bounds__(1024) void scan_c(int* __restrict__ arr,
                                               const int* __restrict__ bsum) {
    int i = blockIdx.x * 1024 + threadIdx.x;
    arr[i] += bsum[blockIdx.x];
}

// group 4096 edges by bucket in LDS, stream out runs at precomputed cursors
__global__ __launch_bounds__(256) void partition_kernel(const int* __restrict__ ei,
                                                        const int* __restrict__ cursor_mat,
                                                        unsigned int* __restrict__ edge_part) {
    __shared__ int h[NBUCK];
    __shared__ int start[NBUCK];
    __shared__ int cur[NBUCK];
    __shared__ int gcur[NBUCK];
    __shared__ unsigned int stage[EPB];
    int t = threadIdx.x;
    h[t] = 0;
    gcur[t] = cursor_mat[t * PBLOCKS + blockIdx.x];
    __syncthreads();
    unsigned int ent[EPB / 256];
    int base = blockIdx.x * EPB;
    #pragma unroll
    for (int i = 0; i < EPB / 256; ++i) {
        int e = base + i * 256 + t;
        int s = ei[e], d = ei[N_EDGES + e];
        ent[i] = ((unsigned int)s << 16) | (unsigned int)d;   // src,dst both < 2^16
        atomicAdd(&h[d >> 8], 1);
    }
    __syncthreads();
    int v = h[t];
    start[t] = v;
    __syncthreads();
    for (int off = 1; off < 256; off <<= 1) {
        int u = (t >= off) ? start[t - off] : 0;
        __syncthreads();
        start[t] += u;
        __syncthreads();
    }
    int excl = start[t] - v;
    start[t] = excl;
    cur[t] = excl;
    __syncthreads();
    #pragma unroll
    for (int i = 0; i < EPB / 256; ++i) {
        int b = (int)((ent[i] & 0xffffu) >> 8);
        int slot = atomicAdd(&cur[b], 1);
        stage[slot] = ent[i];
    }
    __syncthreads();
    int s0 = t * (EPB / 256);   // consecutive slots per thread -> contiguous runs out
    #pragma unroll
    for (int i = 0; i < EPB / 256; ++i) {
        unsigned int p = stage[s0 + i];
        int b = (int)((p & 0xffffu) >> 8);
        edge_part[gcur[b] + (s0 + i - start[b])] = p;
    }
}

// per bucket: local 256-node hist+scan -> row_ptr; scatter src into LDS; stream out
__global__ __launch_bounds__(256) void finalize_kernel(const unsigned int* __restrict__ edge_part,
                                                       const int* __restrict__ cursor_mat,
                                                       int* __restrict__ row_ptr,
                                                       int* __restrict__ csr_src) {
    __shared__ int h[256];
    __shared__ int sc[256];
    __shared__ int cur[256];
    __shared__ unsigned short stage[K4CAP];
    int t = threadIdx.x;
    int b = blockIdx.x;
    int cs = cursor_mat[b * PBLOCKS];
    int ce = (b == NBUCK - 1) ? N_EDGES : cursor_mat[(b + 1) * PBLOCKS];
    int cnt = ce - cs;
    h[t] = 0;
    __syncthreads();
    for (int i = t; i < cnt; i += 256)
        atomicAdd(&h[edge_part[cs + i] & 0xffu], 1);
    __syncthreads();
    int v = h[t];
    sc[t] = v;
    __syncthreads();
    for (int off = 1; off < 256; off <<= 1) {
        int u = (t >= off) ? sc[t - off] : 0;
        __syncthreads();
        sc[t] += u;
        __syncthreads();
    }
    int excl = sc[t] - v;
    row_ptr[b * 256 + t] = cs + excl;
    cur[t] = excl;
    __syncthreads();
    if (cnt <= K4CAP) {
        for (int i = t; i < cnt; i += 256) {
            unsigned int p = edge_part[cs + i];
            int slot = atomicAdd(&cur[p & 0xffu], 1);
            stage[slot] = (unsigned short)(p >> 16);
        }
        __syncthreads();
        for (int i = t; i < cnt; i += 256)
            csr_src[cs + i] = (int)stage[i];
    } else {   // statistically impossible fallback, kept for safety
        for (int i = t; i < cnt; i += 256) {
            unsigned int p = edge_part[cs + i];
            int slot = atomicAdd(&cur[p & 0xffu], 1);
            csr_src[cs + slot] = (int)(p >> 16);
        }
    }
}

// ---------------- GEMM (K=128 fixed, fp32 vector ALU, bf16 W in LDS, bf16 out) ----------------

template <int OUTC>
__global__ __launch_bounds__(256) void gemm_kernel(const float* __restrict__ X,
                                                   const float* __restrict__ W,
                                                   unsigned short* __restrict__ H) {
    extern __shared__ unsigned short Wbf[];   // [128][OUTC] bf16
    constexpr int CQ = OUTC / 4;
    constexpr int NODES_PER_BLOCK = (256 / CQ) * 4;
    for (int i = threadIdx.x; i < 128 * OUTC / 4; i += 256) {
        float4 w = ((const float4*)W)[i];
        ushort4 o;
        o.x = f2bf(w.x); o.y = f2bf(w.y); o.z = f2bf(w.z); o.w = f2bf(w.w);
        ((ushort4*)Wbf)[i] = o;
    }
    __syncthreads();
    int cq = threadIdx.x % CQ;
    int nq = threadIdx.x / CQ;
    int node0 = blockIdx.x * NODES_PER_BLOCK + nq * 4;
    float acc[4][4] = {};
    const float4* x4 = (const float4*)X;
    for (int k4 = 0; k4 < 32; ++k4) {
        float4 xv[4];
        #pragma unroll
        for (int i = 0; i < 4; ++i) xv[i] = x4[(node0 + i) * 32 + k4];
        #pragma unroll
        for (int j = 0; j < 4; ++j) {
            ushort4 wq = ((const ushort4*)(Wbf + (k4 * 4 + j) * OUTC))[cq];
            float w0 = bf2f(wq.x), w1 = bf2f(wq.y), w2 = bf2f(wq.z), w3 = bf2f(wq.w);
            #pragma unroll
            for (int i = 0; i < 4; ++i) {
                float xs = ((const float*)&xv[i])[j];
                acc[i][0] += xs * w0;
                acc[i][1] += xs * w1;
                acc[i][2] += xs * w2;
                acc[i][3] += xs * w3;
            }
        }
    }
    #pragma unroll
    for (int i = 0; i < 4; ++i) {
        ushort4 o;
        o.x = f2bf(acc[i][0]);
        o.y = f2bf(acc[i][1]);
        o.z = f2bf(acc[i][2]);
        o.w = f2bf(acc[i][3]);
        ((ushort4*)(H + (size_t)(node0 + i) * OUTC))[cq] = o;
    }
}

// ---------------- attention logits (bf16 h) ----------------

__global__ __launch_bounds__(256) void att1_kernel(const unsigned int* __restrict__ h1u,
                                                   const float* __restrict__ as_w,
                                                   const float* __restrict__ ad_w,
                                                   float* __restrict__ a_src,
                                                   float* __restrict__ a_dst) {
    int wave = (blockIdx.x * 256 + threadIdx.x) >> 6;
    int lane = threadIdx.x & 63;
    unsigned int p = h1u[wave * 64 + lane];
    float h0 = bflo(p), h1v = bfhi(p);
    float2 sw = *(const float2*)(as_w + lane * 2);
    float2 dw = *(const float2*)(ad_w + lane * 2);
    float ps = h0 * sw.x + h1v * sw.y;
    float pd = h0 * dw.x + h1v * dw.y;
    #pragma unroll
    for (int m = 1; m < 16; m <<= 1) {
        ps += __shfl_xor(ps, m);
        pd += __shfl_xor(pd, m);
    }
    if ((lane & 15) == 0) {
        a_src[wave * 4 + (lane >> 4)] = ps;
        a_dst[wave * 4 + (lane >> 4)] = pd;
    }
}

__global__ __launch_bounds__(256) void att2_kernel(const unsigned short* __restrict__ h2u,
                                                   const float* __restrict__ as_w,
                                                   const float* __restrict__ ad_w,
                                                   float* __restrict__ a_src,
                                                   float* __restrict__ a_dst) {
    int wave = (blockIdx.x * 256 + threadIdx.x) >> 6;
    int lane = threadIdx.x & 63;
    float v = bf2f(h2u[wave * 64 + lane]);
    float ps = v * as_w[lane];
    float pd = v * ad_w[lane];
    #pragma unroll
    for (int m = 1; m < 64; m <<= 1) {
        ps += __shfl_xor(ps, m);
        pd += __shfl_xor(pd, m);
    }
    if (lane == 0) {
        a_src[wave] = ps;
        a_dst[wave] = pd;
    }
}

// ---------------- edge aggregation (softmax fused, bf16 gather, 4x MLP) ----------------

__global__ __launch_bounds__(256) void agg1_kernel(const int* __restrict__ row_ptr,
                                                   const int* __restrict__ csr_src,
                                                   const unsigned int* __restrict__ h1u,
                                                   const float* __restrict__ a_src,
                                                   const float* __restrict__ a_dst,
                                                   const float* __restrict__ b1,
                                                   float* __restrict__ x2) {
    int n = (blockIdx.x * 256 + threadIdx.x) >> 6;
    int lane = threadIdx.x & 63;
    int hd = lane >> 4;
    int c0 = lane * 2;
    float ad = a_dst[n * 4 + hd];
    int e = row_ptr[n], end = row_ptr[n + 1];
    float acc0 = 0.f, acc1 = 0.f, denom = 0.f;
    while (e < end) {
        int m = end - e;
        if (m > 64) m = 64;
        int s_l = (lane < m) ? csr_src[e + lane] : 0;
        int j = 0;
        for (; j + 4 <= m; j += 4) {
            int s0 = __shfl(s_l, j + 0);
            int s1 = __shfl(s_l, j + 1);
            int s2 = __shfl(s_l, j + 2);
            int s3 = __shfl(s_l, j + 3);
            float l0 = a_src[s0 * 4 + hd] + ad;
            float l1 = a_src[s1 * 4 + hd] + ad;
            float l2 = a_src[s2 * 4 + hd] + ad;
            float l3 = a_src[s3 * 4 + hd] + ad;
            unsigned int p0 = h1u[(size_t)s0 * 64 + lane];
            unsigned int p1 = h1u[(size_t)s1 * 64 + lane];
            unsigned int p2 = h1u[(size_t)s2 * 64 + lane];
            unsigned int p3 = h1u[(size_t)s3 * 64 + lane];
            float w0 = lrelu_exp(l0), w1 = lrelu_exp(l1);
            float w2 = lrelu_exp(l2), w3 = lrelu_exp(l3);
            denom += w0 + w1 + w2 + w3;
            acc0 += w0 * bflo(p0) + w1 * bflo(p1) + w2 * bflo(p2) + w3 * bflo(p3);
            acc1 += w0 * bfhi(p0) + w1 * bfhi(p1) + w2 * bfhi(p2) + w3 * bfhi(p3);
        }
        for (; j < m; ++j) {
            int s = __shfl(s_l, j);
            float w = lrelu_exp(a_src[s * 4 + hd] + ad);
            unsigned int p = h1u[(size_t)s * 64 + lane];
            denom += w;
            acc0 += w * bflo(p);
            acc1 += w * bfhi(p);
        }
        e += 64;
    }
    float inv = 1.f / (denom + EPS_);
    float o0 = acc0 * inv + b1[c0];
    float o1 = acc1 * inv + b1[c0 + 1];
    o0 = 1.f / (1.f + __expf(-o0));
    o1 = 1.f / (1.f + __expf(-o1));
    *(float2*)(x2 + (size_t)n * 128 + c0) = make_float2(o0, o1);
}

__global__ __launch_bounds__(256) void agg2_kernel(const int* __restrict__ row_ptr,
                                                   const int* __restrict__ csr_src,
                                                   const unsigned short* __restrict__ h2u,
                                                   const float* __restrict__ a_src,
                                                   const float* __restrict__ a_dst,
                                                   const float* __restrict__ b2,
                                                   float* __restrict__ out) {
    int n = (blockIdx.x * 256 + threadIdx.x) >> 6;
    int lane = threadIdx.x & 63;
    float ad = a_dst[n];
    int e = row_ptr[n], end = row_ptr[n + 1];
    float acc = 0.f, denom = 0.f;
    while (e < end) {
        int m = end - e;
        if (m > 64) m = 64;
        int s_l = (lane < m) ? csr_src[e + lane] : 0;
        int j = 0;
        for (; j + 4 <= m; j += 4) {
            int s0 = __shfl(s_l, j + 0);
            int s1 = __shfl(s_l, j + 1);
            int s2 = __shfl(s_l, j + 2);
            int s3 = __shfl(s_l, j + 3);
            float l0 = a_src[s0] + ad;
            float l1 = a_src[s1] + ad;
            float l2 = a_src[s2] + ad;
            float l3 = a_src[s3] + ad;
            float v0 = bf2f(h2u[(size_t)s0 * 64 + lane]);
            float v1 = bf2f(h2u[(size_t)s1 * 64 + lane]);
            float v2 = bf2f(h2u[(size_t)s2 * 64 + lane]);
            float v3 = bf2f(h2u[(size_t)s3 * 64 + lane]);
            float w0 = lrelu_exp(l0), w1 = lrelu_exp(l1);
            float w2 = lrelu_exp(l2), w3 = lrelu_exp(l3);
            denom += w0 + w1 + w2 + w3;
            acc += w0 * v0 + w1 * v1 + w2 * v2 + w3 * v3;
        }
        for (; j < m; ++j) {
            int s = __shfl(s_l, j);
            float w = lrelu_exp(a_src[s] + ad);
            float v = bf2f(h2u[(size_t)s * 64 + lane]);
            denom += w;
            acc += w * v;
        }
        e += 64;
    }
    float o = acc / (denom + EPS_) + b2[lane];
    out[(size_t)n * 64 + lane] = 1.f / (1.f + __expf(-o));
}

// ---------------- launch ----------------

extern "C" void kernel_launch(void* const* d_in, const int* in_sizes, int n_in,
                              void* d_out, int out_size, void* d_ws, size_t ws_size,
                              hipStream_t stream) {
    (void)in_sizes; (void)n_in; (void)out_size; (void)ws_size;
    const float* x   = (const float*)d_in[0];
    const int*   ei  = (const int*)d_in[1];
    const float* W1  = (const float*)d_in[2];
    const float* as1 = (const float*)d_in[3];
    const float* ad1 = (const float*)d_in[4];
    const float* b1  = (const float*)d_in[5];
    const float* W2  = (const float*)d_in[6];
    const float* as2 = (const float*)d_in[7];
    const float* ad2 = (const float*)d_in[8];
    const float* b2  = (const float*)d_in[9];
    float* out = (float*)d_out;

    char* p = (char*)d_ws;
    auto alloc = [&](size_t bytes) -> void* {
        void* r = (void*)p;
        p += (bytes + 255) & ~(size_t)255;
        return r;
    };
    int* hist_mat   = (int*)alloc((size_t)NBUCK * PBLOCKS * 4);
    int* cursor_mat = (int*)alloc((size_t)NBUCK * PBLOCKS * 4);
    int* bsum       = (int*)alloc(64 * 4);
    unsigned int* edge_part = (unsigned int*)alloc((size_t)N_EDGES * 4);
    int* row_ptr    = (int*)alloc((size_t)(N_NODES + 1) * 4);
    int* csr_src    = (int*)alloc((size_t)N_EDGES * 4);
    unsigned short* h1 = (unsigned short*)alloc((size_t)N_NODES * 128 * 2);
    float* a_src1   = (float*)alloc((size_t)N_NODES * 4 * 4);
    float* a_dst1   = (float*)alloc((size_t)N_NODES * 4 * 4);
    float* x2       = (float*)alloc((size_t)N_NODES * 128 * 4);
    unsigned short* h2 = (unsigned short*)alloc((size_t)N_NODES * 64 * 2);
    float* a_src2   = (float*)alloc((size_t)N_NODES * 4);
    float* a_dst2   = (float*)alloc((size_t)N_NODES * 4);

    // CSR build (atomic-free radix partition)
    coarse_hist<<<PBLOCKS, 256, 0, stream>>>(ei, hist_mat);
    scan_a<<<64, 1024, 0, stream>>>(hist_mat, cursor_mat, bsum);
    scan_b<<<1, 64, 0, stream>>>(bsum, row_ptr);
    scan_c<<<64, 1024, 0, stream>>>(cursor_mat, bsum);
    partition_kernel<<<PBLOCKS, 256, 0, stream>>>(ei, cursor_mat, edge_part);
    finalize_kernel<<<NBUCK, 256, 0, stream>>>(edge_part, cursor_mat, row_ptr, csr_src);

    // layer 1
    gemm_kernel<128><<<N_NODES / 32, 256, 128 * 128 * 2, stream>>>(x, W1, h1);
    att1_kernel<<<N_NODES / 4, 256, 0, stream>>>((const unsigned int*)h1, as1, ad1, a_src1, a_dst1);
    agg1_kernel<<<N_NODES / 4, 256, 0, stream>>>(row_ptr, csr_src, (const unsigned int*)h1,
                                                 a_src1, a_dst1, b1, x2);

    // layer 2
    gemm_kernel<64><<<N_NODES / 64, 256, 128 * 64 * 2, stream>>>(x2, W2, h2);
    att2_kernel<<<N_NODES / 4, 256, 0, stream>>>(h2, as2, ad2, a_src2, a_dst2);
    agg2_kernel<<<N_NODES / 4, 256, 0, stream>>>(row_ptr, csr_src, h2, a_src2, a_dst2, b2, out);
}